// Round 1
// baseline (269.313 us; speedup 1.0000x reference)
//
#include <hip/hip_runtime.h>

// Kernel 1: E[b] = expm(t[b] * A), A = 0.5*(B - B^T), B = M + M0, 8x8.
// One block (64 threads) per t value; thread `lane` owns element (i,j) with
// i = lane>>3, j = lane&7. Taylor series: term_{k} = term_{k-1} * (tA) / k.
// ||tA||_F <~ 0.1 so 12 terms is exact to fp32 roundoff.
__global__ void expm_kernel(const float* __restrict__ M, const float* __restrict__ M0,
                            const float* __restrict__ t, float* __restrict__ E) {
    const int b = blockIdx.x;
    const int lane = threadIdx.x;            // 0..63
    const int i = lane >> 3;
    const int j = lane & 7;

    __shared__ float sA[64];                 // tA
    __shared__ float sP[64];                 // current Taylor term

    const float bij = M[i * 8 + j] + M0[i * 8 + j];
    const float bji = M[j * 8 + i] + M0[j * 8 + i];
    const float ta = t[b] * 0.5f * (bij - bji);

    sA[lane] = ta;
    float e = (i == j ? 1.0f : 0.0f) + ta;   // I + tA
    float p = ta;
    __syncthreads();

    for (int k = 2; k <= 12; ++k) {
        sP[lane] = p;
        __syncthreads();
        float s = 0.0f;
        #pragma unroll
        for (int l = 0; l < 8; ++l) {
            s = fmaf(sP[i * 8 + l], sA[l * 8 + j], s);
        }
        p = s * (1.0f / (float)k);
        e += p;
        __syncthreads();                     // protect sP before next overwrite
    }

    E[b * 64 + lane] = e;
}

// Kernel 2: out[t, n, i] = sum_j E[t][i][j] * x[n][j].
//
// v2: lane-contiguous stores. Each thread owns one OUTPUT float4 SLOT per
// g-iteration: slot s (16 B) covers out[t][s>>1][(s&1)*4 .. (s&1)*4+4).
// Per-block slot base and per-g stride (256) are even, so h = s&1 = tid&1 is
// fixed per thread: the thread computes only its half-matvec (4 of 8 output
// rows) and needs only 32 E values (halved register pressure vs e[64]).
// The store o4[s] is 16 B/lane at 16 B stride -> each global_store_dwordx4
// covers a fully-contiguous 4 KB per block-iteration, the same stream shape
// the harness fill kernel sustains 6.5 TB/s with. (Old version stored
// 16 B/lane at 32 B stride = half-full 64 B sectors, 2x write-path requests.)
// Reads: a lane pair (2k, 2k+1) loads the same two float4s of x -> broadcast
// coalesced, and x (512 KB) is L2-resident, so the duplication is free.
#define APPLY_G 16  // float4 slots per thread (== 8 n-rows, same work as before)

__global__ __launch_bounds__(256) void apply_kernel(const float* __restrict__ Eall,
                                                    const float* __restrict__ x,
                                                    float* __restrict__ out,
                                                    int N) {
    const int t = blockIdx.y;
    const int tid = threadIdx.x;

    __shared__ float sE[64];
    if (tid < 64) sE[tid] = Eall[t * 64 + tid];
    __syncthreads();

    // Thread's half of E: rows h*4 .. h*4+3 live at sE[h*32 .. h*32+32).
    const int h = tid & 1;
    float e2[32];
    #pragma unroll
    for (int c = 0; c < 32; ++c) e2[c] = sE[(h << 5) + c];

    const int S = N * 2;                      // total float4 slots for this t
    const int s0 = blockIdx.x * (256 * APPLY_G) + tid;
    const float4* __restrict__ x4 = (const float4*)x;
    float4* __restrict__ o4 = (float4*)(out + (size_t)t * (size_t)N * 8);

    #pragma unroll
    for (int g = 0; g < APPLY_G; ++g) {
        const int s = s0 + g * 256;
        if (s < S) {
            const int sb = s & ~1;            // 2n: first float4 of x row n
            const float4 a = x4[sb];
            const float4 b = x4[sb + 1];
            const float xs[8] = {a.x, a.y, a.z, a.w, b.x, b.y, b.z, b.w};
            float y0 = 0.0f, y1 = 0.0f, y2 = 0.0f, y3 = 0.0f;
            #pragma unroll
            for (int jj = 0; jj < 8; ++jj) {
                y0 = fmaf(e2[0 * 8 + jj], xs[jj], y0);
                y1 = fmaf(e2[1 * 8 + jj], xs[jj], y1);
                y2 = fmaf(e2[2 * 8 + jj], xs[jj], y2);
                y3 = fmaf(e2[3 * 8 + jj], xs[jj], y3);
            }
            o4[s] = make_float4(y0, y1, y2, y3);  // lane-contiguous 16 B/lane
        }
    }
}

extern "C" void kernel_launch(void* const* d_in, const int* in_sizes, int n_in,
                              void* d_out, int out_size, void* d_ws, size_t ws_size,
                              hipStream_t stream) {
    const float* x  = (const float*)d_in[0];   // [N, 8]
    const float* t  = (const float*)d_in[1];   // [T]
    const float* M  = (const float*)d_in[2];   // [8, 8]
    const float* M0 = (const float*)d_in[3];   // [8, 8]
    float* out = (float*)d_out;                // [T, N, 8]
    float* E = (float*)d_ws;                   // [T, 64] scratch (T*256 bytes)

    const int N = in_sizes[0] / 8;
    const int T = in_sizes[1];

    hipLaunchKernelGGL(expm_kernel, dim3(T), dim3(64), 0, stream, M, M0, t, E);

    const int S = 2 * N;                       // float4 slots per t
    const int gx = (S + 256 * APPLY_G - 1) / (256 * APPLY_G);
    hipLaunchKernelGGL(apply_kernel, dim3(gx, T), dim3(256), 0, stream, E, x, out, N);
}